// Round 9
// baseline (2288.156 us; speedup 1.0000x reference)
//
#include <hip/hip_runtime.h>
#include <hip/hip_bf16.h>

// Problem: B=8, T_OUT=256, T_IN=512, L=128, D_IN=128, D_ATT=128 (f32 in/out).
// R9: two launches. A) fused keys+xz prologue. B) single 258-block kernel:
// blocks 0-1 = R7's 8-wave MFMA scan (R8's 4-wave regressed: chain-latency
// bound, needs TLP); blocks 2-257 = attn tiles that spin on a progress flag
// published by the scan every 8 steps. x crosses XCDs via agent-scope f32
// stores/loads; flags via device atomicMax after vmcnt-drain barrier.
// Co-residency guaranteed: 258 blocks, 58KB LDS -> 2 blocks/CU (512 slots).
//
// ws layout (float elements):
#define PROG_OFF 1048560   // int[2] progress flags (poison 0xAA.. = negative, atomicMax-safe)
#define XZ_OFF   1048576   // f16[8*256*512] region (2 MB)
#define KEYS_OFF 2097152   // f32[8*512*128]
#define X_OFF    2621440   // f32[8*256*128]
// out layout (f32): out(8,256,256) @0, h(8,128) @524288, c(8,128) @525312
#define OUT_H    524288
#define OUT_C    525312

#define LDS_BARRIER()  __asm__ __volatile__("s_waitcnt lgkmcnt(0)\n\ts_barrier" ::: "memory")
#define FULL_BARRIER() __asm__ __volatile__("s_waitcnt vmcnt(0) lgkmcnt(0)\n\ts_barrier" ::: "memory")

typedef _Float16 f16x8 __attribute__((ext_vector_type(8)));
typedef float fx4 __attribute__((ext_vector_type(4)));

__device__ __forceinline__ float fast_rcp(float x) { return __builtin_amdgcn_rcpf(x); }
__device__ __forceinline__ float fast_sig(float v) { return fast_rcp(1.f + __expf(-v)); }
__device__ __forceinline__ float fast_tanh(float v) { return 2.f * fast_rcp(1.f + __expf(-2.f * v)) - 1.f; }

// ---------------- Kernel A: prologue = keys (blocks 0-255) + xz (256-511) ----------------
__global__ __launch_bounds__(256)
void prologue_k(const float* __restrict__ inp, const float* __restrict__ att,
                const float* __restrict__ Wk, const float* __restrict__ bias,
                const float* __restrict__ W1, const float* __restrict__ b1,
                float* __restrict__ ws) {
  __shared__ float ar[16][128];
  const int tid = threadIdx.x;
  if (blockIdx.x < 256) {
    // ---- keys = attended @ W1 + b1 (16 rows/block) ----
    float* keys = ws + KEYS_OFF;
    const int row0 = blockIdx.x * 16;
    for (int i = tid; i < 16 * 128; i += 256) ar[i >> 7][i & 127] = att[row0 * 128 + i];
    __syncthreads();
    const int l = tid & 127, r0 = tid >> 7;
    float acc[8];
    const float bl = b1[l];
#pragma unroll
    for (int i = 0; i < 8; ++i) acc[i] = bl;
    for (int d = 0; d < 128; d += 4) {
      float w0 = W1[(d + 0) * 128 + l], w1 = W1[(d + 1) * 128 + l];
      float w2 = W1[(d + 2) * 128 + l], w3 = W1[(d + 3) * 128 + l];
#pragma unroll
      for (int i = 0; i < 8; ++i) {
        float4 a4 = *(const float4*)&ar[r0 + 2 * i][d];
        acc[i] += a4.x * w0 + a4.y * w1 + a4.z * w2 + a4.w * w3;
      }
    }
#pragma unroll
    for (int i = 0; i < 8; ++i) keys[(row0 + r0 + 2 * i) * 128 + l] = acc[i];
  } else {
    // ---- xz = inputs @ Wk + bias, stored f16 [t][b][u][gate] (8 rows/block) ----
    _Float16* xz16 = (_Float16*)(ws + XZ_OFF);
    const int row0 = (blockIdx.x - 256) * 8;
    for (int i = tid; i < 8 * 128; i += 256) ar[i >> 7][i & 127] = inp[row0 * 128 + i];
    __syncthreads();
    float acc[8][2];
    const float bb0 = bias[tid], bb1 = bias[tid + 256];
#pragma unroll
    for (int r = 0; r < 8; ++r) { acc[r][0] = bb0; acc[r][1] = bb1; }
    for (int d = 0; d < 128; d += 4) {
      float w0a = Wk[(d + 0) * 512 + tid], w0b = Wk[(d + 0) * 512 + tid + 256];
      float w1a = Wk[(d + 1) * 512 + tid], w1b = Wk[(d + 1) * 512 + tid + 256];
      float w2a = Wk[(d + 2) * 512 + tid], w2b = Wk[(d + 2) * 512 + tid + 256];
      float w3a = Wk[(d + 3) * 512 + tid], w3b = Wk[(d + 3) * 512 + tid + 256];
#pragma unroll
      for (int r = 0; r < 8; ++r) {
        float4 a4 = *(const float4*)&ar[r][d];
        acc[r][0] += a4.x * w0a + a4.y * w1a + a4.z * w2a + a4.w * w3a;
        acc[r][1] += a4.x * w0b + a4.y * w1b + a4.z * w2b + a4.w * w3b;
      }
    }
    const int u = tid & 127, g0 = tid >> 7;
#pragma unroll
    for (int r = 0; r < 8; ++r) {
      const int row = row0 + r, b = row >> 8, t = row & 255;
      const int base = ((t * 8 + b) * 128 + u) * 4;
      xz16[base + g0]     = (_Float16)acc[r][0];
      xz16[base + g0 + 2] = (_Float16)acc[r][1];
    }
  }
}

// ---------------- Kernel B: scan (blocks 0-1) + attn (blocks 2-257) ----------------
__global__ __launch_bounds__(512, 4)
void main_k(const float* __restrict__ Wrf, const float* __restrict__ att,
            const float* __restrict__ W2c, const float* __restrict__ b2c,
            const float* __restrict__ W3c, const float* __restrict__ b3c,
            float* __restrict__ ws, float* __restrict__ out) {
  __shared__ __align__(16) char smem[58368];
  const int tid = threadIdx.x;
  float* xf = ws + X_OFF;
  int* prog = (int*)(ws + PROG_OFF);

  if (blockIdx.x < 2) {
    // ======== LSTM scan: R7 8-wave MFMA body ========
    _Float16 (*hb)[552] = (_Float16(*)[552])smem;  // 2 x 4 rows x stride 136
    const _Float16* xz16 = (const _Float16*)(ws + XZ_OFF);
    const int b_base = blockIdx.x * 4;
    const int w = tid >> 6, lane = tid & 63;
    const int q = lane >> 4, p = lane & 15;
    const int b = p & 3, isel = p >> 2;
    const int u = 16 * w + 4 * isel + q;  // lane's unit
    const int bg = b_base + b;

    // A-frags: A[m=p][k=kt*32+q*8+j]; row m -> gatecol (m&3)*128 + 16w + 4i + (m>>2)
    f16x8 afr[4][4];
#pragma unroll
    for (int i = 0; i < 4; ++i) {
      const int col = (p & 3) * 128 + 16 * w + 4 * i + (p >> 2);
#pragma unroll
      for (int kt = 0; kt < 4; ++kt)
#pragma unroll
        for (int j = 0; j < 8; ++j)
          afr[i][kt][j] = (_Float16)Wrf[(kt * 32 + q * 8 + j) * 512 + col];
    }
    {
      _Float16* hp = &hb[0][0];
      for (int i = tid; i < 2 * 552; i += 512) hp[i] = (_Float16)0.f;
    }
    const fx4 zeroC = {0.f, 0.f, 0.f, 0.f};
    float cst = 0.f, hval = 0.f;
    const _Float16* xp = xz16 + (bg * 128 + u) * 4;
    uint2 pf0 = *(const uint2*)(xp);
    uint2 pf1 = *(const uint2*)(xp + 4096);
    uint2 pf2 = *(const uint2*)(xp + 8192);
    __syncthreads();

    const int brow = (p & 3) * 136;  // B broadcast: lanes p>=4 mirror p&3
    for (int t = 0; t < 256; ++t) {
      const _Float16* hrow = &hb[t & 1][brow];
      f16x8 bfr[4];
#pragma unroll
      for (int kt = 0; kt < 4; ++kt)
        bfr[kt] = *(const f16x8*)&hrow[kt * 32 + q * 8];
      fx4 acc[4];
#pragma unroll
      for (int i = 0; i < 4; ++i)
        acc[i] = __builtin_amdgcn_mfma_f32_16x16x32_f16(afr[i][0], bfr[0], zeroC, 0, 0, 0);
#pragma unroll
      for (int kt = 1; kt < 4; ++kt)
#pragma unroll
        for (int i = 0; i < 4; ++i)
          acc[i] = __builtin_amdgcn_mfma_f32_16x16x32_f16(afr[i][kt], bfr[kt], acc[i], 0, 0, 0);

      float z[4];
#pragma unroll
      for (int r = 0; r < 4; ++r) {
        float s01 = (isel & 1) ? acc[1][r] : acc[0][r];
        float s23 = (isel & 1) ? acc[3][r] : acc[2][r];
        z[r] = (isel & 2) ? s23 : s01;
      }

      uint2 cur = pf0;
      pf0 = pf1; pf1 = pf2;
      const int t3 = (t + 3 < 256) ? t + 3 : 255;
      pf2 = *(const uint2*)(xp + t3 * 4096);

      const _Float16* cf = (const _Float16*)&cur;
      const float zi = z[0] + (float)cf[0];
      const float zf = z[1] + (float)cf[1];
      const float zg = z[2] + (float)cf[2];
      const float zo = z[3] + (float)cf[3];
      cst = fast_sig(zf) * cst + fast_sig(zi) * fast_tanh(zg);
      hval = fast_sig(zo) * fast_tanh(cst);
      hb[(t + 1) & 1][b * 136 + u] = (_Float16)hval;
      // x published device-visible (agent scope) for cross-XCD attn readers
      __hip_atomic_store(&xf[(bg * 256 + t) * 128 + u], hval,
                         __ATOMIC_RELAXED, __HIP_MEMORY_SCOPE_AGENT);
      if ((t & 7) == 7) {
        FULL_BARRIER();  // all waves' x stores drained to coherent point
        if (tid == 0) atomicMax(&prog[blockIdx.x], t);
      } else {
        LDS_BARRIER();
      }
    }
    out[OUT_H + bg * 128 + u] = hval;
    out[OUT_C + bg * 128 + u] = cst;
    return;
  }

  // ======== attn: 8 q-rows per block, 512 threads ========
  float (*qp)[128] = (float(*)[128])smem;             // 4096 B
  float (*xr)[128] = (float(*)[128])(smem + 4096);    // 4096 B
  float (*sc)[512] = (float(*)[512])(smem + 8192);    // 16384 B
  float (*kt)[129] = (float(*)[129])(smem + 24576);   // 33024 B
  float* w3s = (float*)(smem + 57600);                // 512 B
  const float* keys = ws + KEYS_OFF;
  const int ab = blockIdx.x - 2;
  const int b = ab >> 5, q0 = (ab & 31) * 8;
  const int g = b >> 2;
  if (tid < 128) w3s[tid] = W3c[tid];
  // spin until scan published x up to t = q0+7 (flag cadence 8 matches tile)
  {
    const int need = q0 + 7;
    while (__hip_atomic_load(&prog[g], __ATOMIC_ACQUIRE, __HIP_MEMORY_SCOPE_AGENT) < need)
      __builtin_amdgcn_s_sleep(32);
  }
  for (int i = tid; i < 8 * 128; i += 512)
    xr[i >> 7][i & 127] = __hip_atomic_load(&xf[(b * 256 + q0) * 128 + i],
                                            __ATOMIC_RELAXED, __HIP_MEMORY_SCOPE_AGENT);
  __syncthreads();
  const int l = tid & 127, r0 = tid >> 7;  // r0 in 0..3
  {
    float qa[2];
    const float bl = b2c[l];
    qa[0] = bl; qa[1] = bl;
    for (int d = 0; d < 128; d += 4) {
      float w0 = W2c[(d + 0) * 128 + l], w1 = W2c[(d + 1) * 128 + l];
      float w2v = W2c[(d + 2) * 128 + l], w3v = W2c[(d + 3) * 128 + l];
#pragma unroll
      for (int i = 0; i < 2; ++i) {
        float4 a4 = *(const float4*)&xr[r0 + 4 * i][d];
        qa[i] += a4.x * w0 + a4.y * w1 + a4.z * w2v + a4.w * w3v;
      }
    }
#pragma unroll
    for (int i = 0; i < 2; ++i) {
      const int rr = r0 + 4 * i;
      qp[rr][l] = qa[i];
      out[(b * 256 + q0 + rr) * 256 + l] = xr[rr][l];
    }
  }
  const float b3v = b3c[0];
  for (int kt0 = 0; kt0 < 512; kt0 += 64) {
    __syncthreads();  // prev tile consumed (and qp ready on first iter)
    for (int i = tid; i < 64 * 128; i += 512)
      kt[i >> 7][i & 127] = keys[(b * 512 + kt0 + (i >> 7)) * 128 + (i & 127)];
    __syncthreads();
    {
      const int rr = tid >> 6, k = tid & 63;  // 8 x 64 = 512 threads
      float acc = 0.f;
      for (int ll = 0; ll < 128; ll += 4) {
        float4 q4 = *(const float4*)&qp[rr][ll];
        float4 w4 = *(const float4*)&w3s[ll];
        acc += fast_tanh(kt[k][ll + 0] + q4.x) * w4.x
             + fast_tanh(kt[k][ll + 1] + q4.y) * w4.y
             + fast_tanh(kt[k][ll + 2] + q4.z) * w4.z
             + fast_tanh(kt[k][ll + 3] + q4.w) * w4.w;
      }
      sc[rr][kt0 + k] = acc + b3v;
    }
  }
  __syncthreads();
  {
    const int wave = tid >> 6, lane = tid & 63;  // wave w owns row w
    float v[8];
#pragma unroll
    for (int i = 0; i < 8; ++i) v[i] = sc[wave][lane + i * 64];
    float m = v[0];
#pragma unroll
    for (int i = 1; i < 8; ++i) m = fmaxf(m, v[i]);
#pragma unroll
    for (int off = 32; off > 0; off >>= 1) m = fmaxf(m, __shfl_xor(m, off));
    float e[8], s = 0.f;
#pragma unroll
    for (int i = 0; i < 8; ++i) { e[i] = __expf(v[i] - m); s += e[i]; }
#pragma unroll
    for (int off = 32; off > 0; off >>= 1) s += __shfl_xor(s, off);
    const float inv = fast_rcp(s);
#pragma unroll
    for (int i = 0; i < 8; ++i) sc[wave][lane + i * 64] = e[i] * inv;
  }
  __syncthreads();
  {
    const float* attb = att + b * 512 * 128;
    float wa[2] = {0.f, 0.f};
    for (int k = 0; k < 512; k += 4) {
      float a0 = attb[(k + 0) * 128 + l];
      float a1 = attb[(k + 1) * 128 + l];
      float a2 = attb[(k + 2) * 128 + l];
      float a3 = attb[(k + 3) * 128 + l];
#pragma unroll
      for (int i = 0; i < 2; ++i) {
        float4 p4 = *(const float4*)&sc[r0 + 4 * i][k];
        wa[i] += p4.x * a0 + p4.y * a1 + p4.z * a2 + p4.w * a3;
      }
    }
#pragma unroll
    for (int i = 0; i < 2; ++i)
      out[(b * 256 + q0 + r0 + 4 * i) * 256 + 128 + l] = wa[i];
  }
}

extern "C" void kernel_launch(void* const* d_in, const int* in_sizes, int n_in,
                              void* d_out, int out_size, void* d_ws, size_t ws_size,
                              hipStream_t stream) {
  const float* inputs   = (const float*)d_in[0];
  const float* attended = (const float*)d_in[1];
  const float* Wk       = (const float*)d_in[2];
  const float* Wr       = (const float*)d_in[3];
  const float* bias     = (const float*)d_in[4];
  const float* W1       = (const float*)d_in[5];
  const float* b1       = (const float*)d_in[6];
  const float* W2       = (const float*)d_in[7];
  const float* b2       = (const float*)d_in[8];
  const float* W3       = (const float*)d_in[9];
  const float* b3       = (const float*)d_in[10];
  float* out = (float*)d_out;
  float* ws = (float*)d_ws;

  hipLaunchKernelGGL(prologue_k, dim3(512), dim3(256), 0, stream,
                     inputs, attended, Wk, bias, W1, b1, ws);
  hipLaunchKernelGGL(main_k, dim3(258), dim3(512), 0, stream,
                     Wr, attended, W2, b2, W3, b3, ws, out);
}

// Round 10
// 559.520 us; speedup vs baseline: 4.0895x; 4.0895x over previous
//
#include <hip/hip_runtime.h>
#include <hip/hip_bf16.h>

// Problem: B=8, T_OUT=256, T_IN=512, L=128, D_IN=128, D_ATT=128 (f32 in/out).
// R10 = R9 architecture with the register strangulation removed:
//   - __launch_bounds__(512) ONLY (R9's ",4" acted as min-blocks -> 64-VGPR
//     cap -> scan spilled to scratch -> 2.3ms). R7's scan body = 72 VGPR.
//   - attn key tile 64->32 rows: LDS 41.6KB -> >=2 blocks/CU co-residency.
// Two launches: A) fused keys+xz prologue. B) 258-block kernel: blocks 0-1 =
// R7 8-wave MFMA scan publishing progress every 8 steps; blocks 2-257 = attn
// tiles spinning on the flag. x crosses XCDs agent-scope; flags device-scope
// after vmcnt drain. Proven correct in R9.
//
// ws layout (float elements):
#define PROG_OFF 1048560   // int[2] progress flags (0xAA poison = negative, atomicMax-safe)
#define XZ_OFF   1048576   // f16[8*256*512] region (2 MB)
#define KEYS_OFF 2097152   // f32[8*512*128]
#define X_OFF    2621440   // f32[8*256*128]
// out layout (f32): out(8,256,256) @0, h(8,128) @524288, c(8,128) @525312
#define OUT_H    524288
#define OUT_C    525312

#define LDS_BARRIER()  __asm__ __volatile__("s_waitcnt lgkmcnt(0)\n\ts_barrier" ::: "memory")
#define FULL_BARRIER() __asm__ __volatile__("s_waitcnt vmcnt(0) lgkmcnt(0)\n\ts_barrier" ::: "memory")

typedef _Float16 f16x8 __attribute__((ext_vector_type(8)));
typedef float fx4 __attribute__((ext_vector_type(4)));

__device__ __forceinline__ float fast_rcp(float x) { return __builtin_amdgcn_rcpf(x); }
__device__ __forceinline__ float fast_sig(float v) { return fast_rcp(1.f + __expf(-v)); }
__device__ __forceinline__ float fast_tanh(float v) { return 2.f * fast_rcp(1.f + __expf(-2.f * v)) - 1.f; }

// ---------------- Kernel A: prologue = keys (blocks 0-255) + xz (256-511) ----------------
__global__ __launch_bounds__(256)
void prologue_k(const float* __restrict__ inp, const float* __restrict__ att,
                const float* __restrict__ Wk, const float* __restrict__ bias,
                const float* __restrict__ W1, const float* __restrict__ b1,
                float* __restrict__ ws) {
  __shared__ float ar[16][128];
  const int tid = threadIdx.x;
  if (blockIdx.x < 256) {
    // ---- keys = attended @ W1 + b1 (16 rows/block) ----
    float* keys = ws + KEYS_OFF;
    const int row0 = blockIdx.x * 16;
    for (int i = tid; i < 16 * 128; i += 256) ar[i >> 7][i & 127] = att[row0 * 128 + i];
    __syncthreads();
    const int l = tid & 127, r0 = tid >> 7;
    float acc[8];
    const float bl = b1[l];
#pragma unroll
    for (int i = 0; i < 8; ++i) acc[i] = bl;
    for (int d = 0; d < 128; d += 4) {
      float w0 = W1[(d + 0) * 128 + l], w1 = W1[(d + 1) * 128 + l];
      float w2 = W1[(d + 2) * 128 + l], w3 = W1[(d + 3) * 128 + l];
#pragma unroll
      for (int i = 0; i < 8; ++i) {
        float4 a4 = *(const float4*)&ar[r0 + 2 * i][d];
        acc[i] += a4.x * w0 + a4.y * w1 + a4.z * w2 + a4.w * w3;
      }
    }
#pragma unroll
    for (int i = 0; i < 8; ++i) keys[(row0 + r0 + 2 * i) * 128 + l] = acc[i];
  } else {
    // ---- xz = inputs @ Wk + bias, stored f16 [t][b][u][gate] (8 rows/block) ----
    _Float16* xz16 = (_Float16*)(ws + XZ_OFF);
    const int row0 = (blockIdx.x - 256) * 8;
    for (int i = tid; i < 8 * 128; i += 256) ar[i >> 7][i & 127] = inp[row0 * 128 + i];
    __syncthreads();
    float acc[8][2];
    const float bb0 = bias[tid], bb1 = bias[tid + 256];
#pragma unroll
    for (int r = 0; r < 8; ++r) { acc[r][0] = bb0; acc[r][1] = bb1; }
    for (int d = 0; d < 128; d += 4) {
      float w0a = Wk[(d + 0) * 512 + tid], w0b = Wk[(d + 0) * 512 + tid + 256];
      float w1a = Wk[(d + 1) * 512 + tid], w1b = Wk[(d + 1) * 512 + tid + 256];
      float w2a = Wk[(d + 2) * 512 + tid], w2b = Wk[(d + 2) * 512 + tid + 256];
      float w3a = Wk[(d + 3) * 512 + tid], w3b = Wk[(d + 3) * 512 + tid + 256];
#pragma unroll
      for (int r = 0; r < 8; ++r) {
        float4 a4 = *(const float4*)&ar[r][d];
        acc[r][0] += a4.x * w0a + a4.y * w1a + a4.z * w2a + a4.w * w3a;
        acc[r][1] += a4.x * w0b + a4.y * w1b + a4.z * w2b + a4.w * w3b;
      }
    }
    const int u = tid & 127, g0 = tid >> 7;
#pragma unroll
    for (int r = 0; r < 8; ++r) {
      const int row = row0 + r, b = row >> 8, t = row & 255;
      const int base = ((t * 8 + b) * 128 + u) * 4;
      xz16[base + g0]     = (_Float16)acc[r][0];
      xz16[base + g0 + 2] = (_Float16)acc[r][1];
    }
  }
}

// ---------------- Kernel B: scan (blocks 0-1) + attn (blocks 2-257) ----------------
__global__ __launch_bounds__(512)
void main_k(const float* __restrict__ Wrf, const float* __restrict__ att,
            const float* __restrict__ W2c, const float* __restrict__ b2c,
            const float* __restrict__ W3c, const float* __restrict__ b3c,
            float* __restrict__ ws, float* __restrict__ out) {
  __shared__ __align__(16) char smem[41600];
  const int tid = threadIdx.x;
  float* xf = ws + X_OFF;
  int* prog = (int*)(ws + PROG_OFF);

  if (blockIdx.x < 2) {
    // ======== LSTM scan: R7 8-wave MFMA body (72 VGPR, no spills) ========
    _Float16 (*hb)[552] = (_Float16(*)[552])smem;  // 2 x 4 rows x stride 136
    const _Float16* xz16 = (const _Float16*)(ws + XZ_OFF);
    const int b_base = blockIdx.x * 4;
    const int w = tid >> 6, lane = tid & 63;
    const int q = lane >> 4, p = lane & 15;
    const int b = p & 3, isel = p >> 2;
    const int u = 16 * w + 4 * isel + q;  // lane's unit
    const int bg = b_base + b;

    f16x8 afr[4][4];
#pragma unroll
    for (int i = 0; i < 4; ++i) {
      const int col = (p & 3) * 128 + 16 * w + 4 * i + (p >> 2);
#pragma unroll
      for (int kt = 0; kt < 4; ++kt)
#pragma unroll
        for (int j = 0; j < 8; ++j)
          afr[i][kt][j] = (_Float16)Wrf[(kt * 32 + q * 8 + j) * 512 + col];
    }
    {
      _Float16* hp = &hb[0][0];
      for (int i = tid; i < 2 * 552; i += 512) hp[i] = (_Float16)0.f;
    }
    const fx4 zeroC = {0.f, 0.f, 0.f, 0.f};
    float cst = 0.f, hval = 0.f;
    const _Float16* xp = xz16 + (bg * 128 + u) * 4;
    uint2 pf0 = *(const uint2*)(xp);
    uint2 pf1 = *(const uint2*)(xp + 4096);
    uint2 pf2 = *(const uint2*)(xp + 8192);
    __syncthreads();

    const int brow = (p & 3) * 136;
    for (int t = 0; t < 256; ++t) {
      const _Float16* hrow = &hb[t & 1][brow];
      f16x8 bfr[4];
#pragma unroll
      for (int kt = 0; kt < 4; ++kt)
        bfr[kt] = *(const f16x8*)&hrow[kt * 32 + q * 8];
      fx4 acc[4];
#pragma unroll
      for (int i = 0; i < 4; ++i)
        acc[i] = __builtin_amdgcn_mfma_f32_16x16x32_f16(afr[i][0], bfr[0], zeroC, 0, 0, 0);
#pragma unroll
      for (int kt = 1; kt < 4; ++kt)
#pragma unroll
        for (int i = 0; i < 4; ++i)
          acc[i] = __builtin_amdgcn_mfma_f32_16x16x32_f16(afr[i][kt], bfr[kt], acc[i], 0, 0, 0);

      float z[4];
#pragma unroll
      for (int r = 0; r < 4; ++r) {
        float s01 = (isel & 1) ? acc[1][r] : acc[0][r];
        float s23 = (isel & 1) ? acc[3][r] : acc[2][r];
        z[r] = (isel & 2) ? s23 : s01;
      }

      uint2 cur = pf0;
      pf0 = pf1; pf1 = pf2;
      const int t3 = (t + 3 < 256) ? t + 3 : 255;
      pf2 = *(const uint2*)(xp + t3 * 4096);

      const _Float16* cf = (const _Float16*)&cur;
      const float zi = z[0] + (float)cf[0];
      const float zf = z[1] + (float)cf[1];
      const float zg = z[2] + (float)cf[2];
      const float zo = z[3] + (float)cf[3];
      cst = fast_sig(zf) * cst + fast_sig(zi) * fast_tanh(zg);
      hval = fast_sig(zo) * fast_tanh(cst);
      hb[(t + 1) & 1][b * 136 + u] = (_Float16)hval;
      __hip_atomic_store(&xf[(bg * 256 + t) * 128 + u], hval,
                         __ATOMIC_RELAXED, __HIP_MEMORY_SCOPE_AGENT);
      if ((t & 7) == 7) {
        FULL_BARRIER();  // drain x stores to coherent point
        if (tid == 0) atomicMax(&prog[blockIdx.x], t);
      } else {
        LDS_BARRIER();
      }
    }
    out[OUT_H + bg * 128 + u] = hval;
    out[OUT_C + bg * 128 + u] = cst;
    return;
  }

  // ======== attn: 8 q-rows per block, 512 threads, 32-key tiles ========
  float (*qp)[128] = (float(*)[128])smem;             // 4096 B
  float (*xr)[128] = (float(*)[128])(smem + 4096);    // 4096 B
  float (*sc)[512] = (float(*)[512])(smem + 8192);    // 16384 B
  float (*kt)[129] = (float(*)[129])(smem + 24576);   // 16512 B
  float* w3s = (float*)(smem + 41088);                // 512 B
  const float* keys = ws + KEYS_OFF;
  const int ab = blockIdx.x - 2;
  const int b = ab >> 5, q0 = (ab & 31) * 8;
  const int g = b >> 2;
  if (tid < 128) w3s[tid] = W3c[tid];
  {
    const int need = q0 + 7;
    while (__hip_atomic_load(&prog[g], __ATOMIC_ACQUIRE, __HIP_MEMORY_SCOPE_AGENT) < need)
      __builtin_amdgcn_s_sleep(32);
  }
  for (int i = tid; i < 8 * 128; i += 512)
    xr[i >> 7][i & 127] = __hip_atomic_load(&xf[(b * 256 + q0) * 128 + i],
                                            __ATOMIC_RELAXED, __HIP_MEMORY_SCOPE_AGENT);
  __syncthreads();
  const int l = tid & 127, r0 = tid >> 7;  // r0 in 0..3
  {
    float qa[2];
    const float bl = b2c[l];
    qa[0] = bl; qa[1] = bl;
    for (int d = 0; d < 128; d += 4) {
      float w0 = W2c[(d + 0) * 128 + l], w1 = W2c[(d + 1) * 128 + l];
      float w2v = W2c[(d + 2) * 128 + l], w3v = W2c[(d + 3) * 128 + l];
#pragma unroll
      for (int i = 0; i < 2; ++i) {
        float4 a4 = *(const float4*)&xr[r0 + 4 * i][d];
        qa[i] += a4.x * w0 + a4.y * w1 + a4.z * w2v + a4.w * w3v;
      }
    }
#pragma unroll
    for (int i = 0; i < 2; ++i) {
      const int rr = r0 + 4 * i;
      qp[rr][l] = qa[i];
      out[(b * 256 + q0 + rr) * 256 + l] = xr[rr][l];
    }
  }
  const float b3v = b3c[0];
  for (int kt0 = 0; kt0 < 512; kt0 += 32) {
    __syncthreads();  // prev tile consumed (and qp ready on first iter)
    for (int i = tid; i < 32 * 128; i += 512)
      kt[i >> 7][i & 127] = keys[(b * 512 + kt0 + (i >> 7)) * 128 + (i & 127)];
    __syncthreads();
    {
      const int rr = tid >> 6, kk = (tid & 63) >> 1, half = tid & 1;  // 8r x 32k x 2half
      float acc = 0.f;
      for (int ll = half * 64; ll < half * 64 + 64; ll += 4) {
        float4 q4 = *(const float4*)&qp[rr][ll];
        float4 w4 = *(const float4*)&w3s[ll];
        acc += fast_tanh(kt[kk][ll + 0] + q4.x) * w4.x
             + fast_tanh(kt[kk][ll + 1] + q4.y) * w4.y
             + fast_tanh(kt[kk][ll + 2] + q4.z) * w4.z
             + fast_tanh(kt[kk][ll + 3] + q4.w) * w4.w;
      }
      acc += __shfl_xor(acc, 1);  // combine halves
      if (half == 0) sc[rr][kt0 + kk] = acc + b3v;
    }
  }
  __syncthreads();
  {
    const int wave = tid >> 6, lane = tid & 63;  // wave w owns row w
    float v[8];
#pragma unroll
    for (int i = 0; i < 8; ++i) v[i] = sc[wave][lane + i * 64];
    float m = v[0];
#pragma unroll
    for (int i = 1; i < 8; ++i) m = fmaxf(m, v[i]);
#pragma unroll
    for (int off = 32; off > 0; off >>= 1) m = fmaxf(m, __shfl_xor(m, off));
    float e[8], s = 0.f;
#pragma unroll
    for (int i = 0; i < 8; ++i) { e[i] = __expf(v[i] - m); s += e[i]; }
#pragma unroll
    for (int off = 32; off > 0; off >>= 1) s += __shfl_xor(s, off);
    const float inv = fast_rcp(s);
#pragma unroll
    for (int i = 0; i < 8; ++i) sc[wave][lane + i * 64] = e[i] * inv;
  }
  __syncthreads();
  {
    const float* attb = att + b * 512 * 128;
    float wa[2] = {0.f, 0.f};
    for (int k = 0; k < 512; k += 4) {
      float a0 = attb[(k + 0) * 128 + l];
      float a1 = attb[(k + 1) * 128 + l];
      float a2 = attb[(k + 2) * 128 + l];
      float a3 = attb[(k + 3) * 128 + l];
#pragma unroll
      for (int i = 0; i < 2; ++i) {
        float4 p4 = *(const float4*)&sc[r0 + 4 * i][k];
        wa[i] += p4.x * a0 + p4.y * a1 + p4.z * a2 + p4.w * a3;
      }
    }
#pragma unroll
    for (int i = 0; i < 2; ++i)
      out[(b * 256 + q0 + r0 + 4 * i) * 256 + 128 + l] = wa[i];
  }
}

extern "C" void kernel_launch(void* const* d_in, const int* in_sizes, int n_in,
                              void* d_out, int out_size, void* d_ws, size_t ws_size,
                              hipStream_t stream) {
  const float* inputs   = (const float*)d_in[0];
  const float* attended = (const float*)d_in[1];
  const float* Wk       = (const float*)d_in[2];
  const float* Wr       = (const float*)d_in[3];
  const float* bias     = (const float*)d_in[4];
  const float* W1       = (const float*)d_in[5];
  const float* b1       = (const float*)d_in[6];
  const float* W2       = (const float*)d_in[7];
  const float* b2       = (const float*)d_in[8];
  const float* W3       = (const float*)d_in[9];
  const float* b3       = (const float*)d_in[10];
  float* out = (float*)d_out;
  float* ws = (float*)d_ws;

  hipLaunchKernelGGL(prologue_k, dim3(512), dim3(256), 0, stream,
                     inputs, attended, Wk, bias, W1, b1, ws);
  hipLaunchKernelGGL(main_k, dim3(258), dim3(512), 0, stream,
                     Wr, attended, W2, b2, W3, b3, ws, out);
}

// Round 11
// 314.589 us; speedup vs baseline: 7.2735x; 1.7786x over previous
//
#include <hip/hip_runtime.h>
#include <hip/hip_bf16.h>

// Problem: B=8, T_OUT=256, T_IN=512, L=128, D_IN=128, D_ATT=128 (f32 in/out).
// R11: two launches, R10's lesson applied — sync OFF the scan's per-step path.
//  Launch 1 (main_k, 258 blocks x 512 thr):
//   blocks 2-257: xz producer (8 rows) -> release atomicAdd(cnt) -> keys (16 rows)
//   blocks 0-1:   load A-frags, ONE startup acquire-spin until cnt==poison+256,
//                 then R7's 8-wave MFMA scan verbatim (plain f16 x stores,
//                 LDS_BARRIER only — no per-step vmcnt drains / atomics).
//   Deadlock-free: 10.4KB LDS, ~90 VGPR -> all 258 blocks co-resident.
//  Launch 2: R7's 512-block attn (x crosses via launch boundary).
// Counter trick: ws is poisoned 0xAA before every run -> cnt starts at
// 0xAAAAAAAA; 256 producers add 1 each; target = (int)0xAAAAAAAA + 256.
//
// ws layout (float elements): cnt @0 (int), rest as before:
#define XZ_OFF   1048576   // f16[8*256*512] region (2 MB)
#define KEYS_OFF 2097152   // f32[8*512*128]
#define X_OFF    2621440   // f16[8*256*128] region
// out layout (f32): out(8,256,256) @0, h(8,128) @524288, c(8,128) @525312
#define OUT_H    524288
#define OUT_C    525312

#define LDS_BARRIER() __asm__ __volatile__("s_waitcnt lgkmcnt(0)\n\ts_barrier" ::: "memory")

typedef _Float16 f16x8 __attribute__((ext_vector_type(8)));
typedef float fx4 __attribute__((ext_vector_type(4)));

__device__ __forceinline__ float fast_rcp(float x) { return __builtin_amdgcn_rcpf(x); }
__device__ __forceinline__ float fast_sig(float v) { return fast_rcp(1.f + __expf(-v)); }
__device__ __forceinline__ float fast_tanh(float v) { return 2.f * fast_rcp(1.f + __expf(-2.f * v)) - 1.f; }

// ---------------- Kernel 1: producers (xz+keys) + scan ----------------
__global__ __launch_bounds__(512)
void main_k(const float* __restrict__ inp, const float* __restrict__ att,
            const float* __restrict__ Wk, const float* __restrict__ bias,
            const float* __restrict__ W1, const float* __restrict__ b1,
            const float* __restrict__ Wrf, float* __restrict__ ws,
            float* __restrict__ out) {
  __shared__ _Float16 hb[2][552];   // scan: h dbuf, 4 rows x stride 136
  __shared__ float ar[16][128];     // producers: staging
  const int tid = threadIdx.x;
  int* cnt = (int*)ws;
  const int target = (int)0xAAAAAAAA + 256;

  if (blockIdx.x >= 2) {
    // ======== producer: xz (8 rows, col=tid) ========
    _Float16* xz16 = (_Float16*)(ws + XZ_OFF);
    const int row0 = (blockIdx.x - 2) * 8;
    for (int i = tid; i < 8 * 128; i += 512) ar[i >> 7][i & 127] = inp[row0 * 128 + i];
    __syncthreads();
    {
      float acc[8];
      const float bb = bias[tid];
#pragma unroll
      for (int r = 0; r < 8; ++r) acc[r] = bb;
      for (int d = 0; d < 128; d += 4) {
        float w0 = Wk[(d + 0) * 512 + tid], w1 = Wk[(d + 1) * 512 + tid];
        float w2 = Wk[(d + 2) * 512 + tid], w3 = Wk[(d + 3) * 512 + tid];
#pragma unroll
        for (int r = 0; r < 8; ++r) {
          float4 a4 = *(const float4*)&ar[r][d];
          acc[r] += a4.x * w0 + a4.y * w1 + a4.z * w2 + a4.w * w3;
        }
      }
      // Wk col = g*128 + u (Keras gate blocks) -> ((t*8+b)*128+u)*4+g
      const int u = tid & 127, g = tid >> 7;
#pragma unroll
      for (int r = 0; r < 8; ++r) {
        const int row = row0 + r, b = row >> 8, t = row & 255;
        xz16[((t * 8 + b) * 128 + u) * 4 + g] = (_Float16)acc[r];
      }
    }
    __syncthreads();  // drains xz stores (vmcnt 0) + ar reuse safety
    if (tid == 0)
      __hip_atomic_fetch_add(cnt, 1, __ATOMIC_RELEASE, __HIP_MEMORY_SCOPE_AGENT);
    // ======== producer: keys (16 rows) — overlaps the scan ========
    {
      float* keys = ws + KEYS_OFF;
      const int row0k = (blockIdx.x - 2) * 16;
      for (int i = tid; i < 16 * 128; i += 512) ar[i >> 7][i & 127] = att[row0k * 128 + i];
      __syncthreads();
      const int l = tid & 127, r0 = tid >> 7;  // r0 in 0..3
      float acc[4];
      const float bl = b1[l];
#pragma unroll
      for (int i = 0; i < 4; ++i) acc[i] = bl;
      for (int d = 0; d < 128; d += 4) {
        float w0 = W1[(d + 0) * 128 + l], w1 = W1[(d + 1) * 128 + l];
        float w2 = W1[(d + 2) * 128 + l], w3 = W1[(d + 3) * 128 + l];
#pragma unroll
        for (int i = 0; i < 4; ++i) {
          float4 a4 = *(const float4*)&ar[r0 + 4 * i][d];
          acc[i] += a4.x * w0 + a4.y * w1 + a4.z * w2 + a4.w * w3;
        }
      }
#pragma unroll
      for (int i = 0; i < 4; ++i) keys[(row0k + r0 + 4 * i) * 128 + l] = acc[i];
    }
    return;
  }

  // ======== scan: R7 8-wave MFMA body, sync only at startup ========
  const _Float16* xz16 = (const _Float16*)(ws + XZ_OFF);
  _Float16* x16 = (_Float16*)(ws + X_OFF);
  const int b_base = blockIdx.x * 4;
  const int w = tid >> 6, lane = tid & 63;
  const int q = lane >> 4, p = lane & 15;
  const int b = p & 3, isel = p >> 2;
  const int u = 16 * w + 4 * isel + q;  // lane's unit
  const int bg = b_base + b;

  // A-frags load overlaps producers' xz work
  f16x8 afr[4][4];
#pragma unroll
  for (int i = 0; i < 4; ++i) {
    const int col = (p & 3) * 128 + 16 * w + 4 * i + (p >> 2);
#pragma unroll
    for (int kt = 0; kt < 4; ++kt)
#pragma unroll
      for (int j = 0; j < 8; ++j)
        afr[i][kt][j] = (_Float16)Wrf[(kt * 32 + q * 8 + j) * 512 + col];
  }
  {
    _Float16* hp = &hb[0][0];
    for (int i = tid; i < 2 * 552; i += 512) hp[i] = (_Float16)0.f;
  }
  // startup spin: wait for all 256 xz producers (one lane polls; acquire
  // makes their released stores visible; __syncthreads covers the block)
  if (tid == 0) {
    while (__hip_atomic_load(cnt, __ATOMIC_ACQUIRE, __HIP_MEMORY_SCOPE_AGENT) != target)
      __builtin_amdgcn_s_sleep(8);
  }
  __syncthreads();

  const fx4 zeroC = {0.f, 0.f, 0.f, 0.f};
  float cst = 0.f, hval = 0.f;
  const _Float16* xp = xz16 + (bg * 128 + u) * 4;
  uint2 pf0 = *(const uint2*)(xp);
  uint2 pf1 = *(const uint2*)(xp + 4096);
  uint2 pf2 = *(const uint2*)(xp + 8192);

  const int brow = (p & 3) * 136;  // B broadcast: lanes p>=4 mirror p&3
  for (int t = 0; t < 256; ++t) {
    const _Float16* hrow = &hb[t & 1][brow];
    f16x8 bfr[4];
#pragma unroll
    for (int kt = 0; kt < 4; ++kt)
      bfr[kt] = *(const f16x8*)&hrow[kt * 32 + q * 8];
    fx4 acc[4];
#pragma unroll
    for (int i = 0; i < 4; ++i)
      acc[i] = __builtin_amdgcn_mfma_f32_16x16x32_f16(afr[i][0], bfr[0], zeroC, 0, 0, 0);
#pragma unroll
    for (int kt = 1; kt < 4; ++kt)
#pragma unroll
      for (int i = 0; i < 4; ++i)
        acc[i] = __builtin_amdgcn_mfma_f32_16x16x32_f16(afr[i][kt], bfr[kt], acc[i], 0, 0, 0);

    // select MFMA i = isel (2-bit cndmask tree)
    float z[4];
#pragma unroll
    for (int r = 0; r < 4; ++r) {
      float s01 = (isel & 1) ? acc[1][r] : acc[0][r];
      float s23 = (isel & 1) ? acc[3][r] : acc[2][r];
      z[r] = (isel & 2) ? s23 : s01;
    }

    uint2 cur = pf0;
    pf0 = pf1; pf1 = pf2;
    const int t3 = (t + 3 < 256) ? t + 3 : 255;
    pf2 = *(const uint2*)(xp + t3 * 4096);

    const _Float16* cf = (const _Float16*)&cur;
    const float zi = z[0] + (float)cf[0];
    const float zf = z[1] + (float)cf[1];
    const float zg = z[2] + (float)cf[2];
    const float zo = z[3] + (float)cf[3];
    cst = fast_sig(zf) * cst + fast_sig(zi) * fast_tanh(zg);
    hval = fast_sig(zo) * fast_tanh(cst);
    hb[(t + 1) & 1][b * 136 + u] = (_Float16)hval;
    x16[(bg * 256 + t) * 128 + u] = (_Float16)hval;
    LDS_BARRIER();  // LDS visibility only; no vmcnt drain
  }
  out[OUT_H + bg * 128 + u] = hval;
  out[OUT_C + bg * 128 + u] = cst;
}

// ---------------- Kernel 2: qproj + scores + softmax + weighted + concat ----------------
// R7 verbatim: 512 blocks (4 q-rows each), 256 threads.
__global__ __launch_bounds__(256)
void attn_out_k(const float* __restrict__ att, const float* __restrict__ W2c,
                const float* __restrict__ b2c, const float* __restrict__ W3c,
                const float* __restrict__ b3c, const float* __restrict__ ws,
                float* __restrict__ out) {
  const float* keys = ws + KEYS_OFF;
  const _Float16* x16 = (const _Float16*)(ws + X_OFF);
  __shared__ float qp[4][128];
  __shared__ float xr[4][128];
  __shared__ float sc[4][512];
  __shared__ float kt[64][129];
  __shared__ float w3s[128];
  const int tid = threadIdx.x;
  const int b = blockIdx.x >> 6, q0 = (blockIdx.x & 63) * 4;
  const int l = tid & 127, r0 = tid >> 7;  // r0 in 0..1
  if (tid < 128) w3s[tid] = W3c[tid];
  for (int i = tid; i < 4 * 128; i += 256)
    xr[i >> 7][i & 127] = (float)x16[(b * 256 + q0) * 128 + i];
  __syncthreads();
  {
    float qa[2];
    const float bl = b2c[l];
    qa[0] = bl; qa[1] = bl;
    for (int d = 0; d < 128; d += 4) {
      float w0 = W2c[(d + 0) * 128 + l], w1 = W2c[(d + 1) * 128 + l];
      float w2v = W2c[(d + 2) * 128 + l], w3v = W2c[(d + 3) * 128 + l];
#pragma unroll
      for (int i = 0; i < 2; ++i) {
        float4 a4 = *(const float4*)&xr[r0 + 2 * i][d];
        qa[i] += a4.x * w0 + a4.y * w1 + a4.z * w2v + a4.w * w3v;
      }
    }
#pragma unroll
    for (int i = 0; i < 2; ++i) {
      int rr = r0 + 2 * i;
      qp[rr][l] = qa[i];
      out[(b * 256 + q0 + rr) * 256 + l] = xr[rr][l];
    }
  }
  const float b3v = b3c[0];
  for (int kt0 = 0; kt0 < 512; kt0 += 64) {
    __syncthreads();
    for (int i = tid; i < 64 * 128; i += 256)
      kt[i >> 7][i & 127] = keys[(b * 512 + kt0 + (i >> 7)) * 128 + (i & 127)];
    __syncthreads();
    {
      const int rr = tid >> 6, k = tid & 63;
      float acc = 0.f;
      for (int ll = 0; ll < 128; ll += 4) {
        float4 q4 = *(const float4*)&qp[rr][ll];
        float4 w4 = *(const float4*)&w3s[ll];
        acc += fast_tanh(kt[k][ll + 0] + q4.x) * w4.x
             + fast_tanh(kt[k][ll + 1] + q4.y) * w4.y
             + fast_tanh(kt[k][ll + 2] + q4.z) * w4.z
             + fast_tanh(kt[k][ll + 3] + q4.w) * w4.w;
      }
      sc[rr][kt0 + k] = acc + b3v;
    }
  }
  __syncthreads();
  {
    const int wave = tid >> 6, lane = tid & 63;
    float v[8];
#pragma unroll
    for (int i = 0; i < 8; ++i) v[i] = sc[wave][lane + i * 64];
    float m = v[0];
#pragma unroll
    for (int i = 1; i < 8; ++i) m = fmaxf(m, v[i]);
#pragma unroll
    for (int off = 32; off > 0; off >>= 1) m = fmaxf(m, __shfl_xor(m, off));
    float e[8], s = 0.f;
#pragma unroll
    for (int i = 0; i < 8; ++i) { e[i] = __expf(v[i] - m); s += e[i]; }
#pragma unroll
    for (int off = 32; off > 0; off >>= 1) s += __shfl_xor(s, off);
    const float inv = fast_rcp(s);
#pragma unroll
    for (int i = 0; i < 8; ++i) sc[wave][lane + i * 64] = e[i] * inv;
  }
  __syncthreads();
  {
    const float* attb = att + b * 512 * 128;
    float wa[2] = {0.f, 0.f};
    for (int k = 0; k < 512; k += 4) {
      float a0 = attb[(k + 0) * 128 + l];
      float a1 = attb[(k + 1) * 128 + l];
      float a2 = attb[(k + 2) * 128 + l];
      float a3 = attb[(k + 3) * 128 + l];
#pragma unroll
      for (int i = 0; i < 2; ++i) {
        float4 p4 = *(const float4*)&sc[r0 + 2 * i][k];
        wa[i] += p4.x * a0 + p4.y * a1 + p4.z * a2 + p4.w * a3;
      }
    }
#pragma unroll
    for (int i = 0; i < 2; ++i)
      out[(b * 256 + q0 + r0 + 2 * i) * 256 + 128 + l] = wa[i];
  }
}

extern "C" void kernel_launch(void* const* d_in, const int* in_sizes, int n_in,
                              void* d_out, int out_size, void* d_ws, size_t ws_size,
                              hipStream_t stream) {
  const float* inputs   = (const float*)d_in[0];
  const float* attended = (const float*)d_in[1];
  const float* Wk       = (const float*)d_in[2];
  const float* Wr       = (const float*)d_in[3];
  const float* bias     = (const float*)d_in[4];
  const float* W1       = (const float*)d_in[5];
  const float* b1       = (const float*)d_in[6];
  const float* W2       = (const float*)d_in[7];
  const float* b2       = (const float*)d_in[8];
  const float* W3       = (const float*)d_in[9];
  const float* b3       = (const float*)d_in[10];
  float* out = (float*)d_out;
  float* ws = (float*)d_ws;

  hipLaunchKernelGGL(main_k, dim3(258), dim3(512), 0, stream,
                     inputs, attended, Wk, bias, W1, b1, Wr, ws, out);
  hipLaunchKernelGGL(attn_out_k, dim3(512), dim3(256), 0, stream,
                     attended, W2, b2, W3, b3, ws, out);
}